// Round 8
// baseline (185.246 us; speedup 1.0000x reference)
//
#include <hip/hip_runtime.h>
#include <hip/hip_bf16.h>

// Problem constants
#define NB 2
#define NI 384
#define NE 64
#define NH 8
#define NNI (NI*NI)                 // 147456
#define NROWS (NB*NNI)              // 294912
#define MCOLS (NI*8)                // 3072
#define PLANE ((size_t)NI*MCOLS)    // 1179648 elems per (b,h) Va plane
#define KPAD 392                    // padded K stride for bf16 planes (784 B rows, 16B-aligned)
#define VPLANE_E ((size_t)MCOLS*KPAD)   // 1204224 elems per V plane
#define APLANE_E ((size_t)NI*KPAD)      // 150528 elems per A plane

typedef __attribute__((ext_vector_type(8))) short short8;
typedef __attribute__((ext_vector_type(4))) float floatx4;

struct alignas(8) US4 { unsigned short x, y, z, w; };

__device__ __forceinline__ float bf2f(unsigned short u){ return __uint_as_float(((unsigned)u) << 16); }
__device__ __forceinline__ unsigned short f2bf(float f){
    unsigned x = __float_as_uint(f);
    x += 0x7fffu + ((x >> 16) & 1u);          // round-to-nearest-even
    return (unsigned short)(x >> 16);
}

__device__ __forceinline__ float wave_sum(float v){
    #pragma unroll
    for (int m = 32; m > 0; m >>= 1) v += __shfl_xor(v, m, 64);
    return v;
}
__device__ __forceinline__ float wave_max(float v){
    #pragma unroll
    for (int m = 32; m > 0; m >>= 1) v = fmaxf(v, __shfl_xor(v, m, 64));
    return v;
}

// async global->LDS, 16B per lane; LDS dest is wave-uniform base + lane*16
__device__ __forceinline__ void gl_lds16(const unsigned short* g, unsigned short* l){
    __builtin_amdgcn_global_load_lds(
        (__attribute__((address_space(1))) void*)(g),
        (__attribute__((address_space(3))) void*)(l), 16, 0, 0);
}

// ---------------------------------------------------------------------------
// k_w: weight prep (unchanged from validated round-5 kernel).
// ---------------------------------------------------------------------------
__global__ __launch_bounds__(256) void k_w(
    const float* __restrict__ Wv, const float* __restrict__ Weg,
    const float* __restrict__ bV, const float* __restrict__ bEG,
    const float* __restrict__ Wo,
    unsigned short* __restrict__ WtA, unsigned short* __restrict__ WtB,
    float* __restrict__ bcoA, float* __restrict__ bcoB,
    unsigned short* __restrict__ WoT)
{
    const int t = threadIdx.x;
    for (int idx = t; idx < 5120; idx += 256){
        int n = idx >> 6, k = idx & 63;
        WtA[idx] = f2bf((n < 64) ? Wv[k*128 + n]      : Weg[k*32 + (n-64)]);
        WtB[idx] = f2bf((n < 64) ? Wv[k*128 + 64 + n] : Weg[k*32 + 16 + (n-64)]);
    }
    for (int idx = t; idx < 8192; idx += 256){
        int o = idx >> 7, c = idx & 127;
        int r = (c & 7)*16 + (c >> 3);
        WoT[idx] = f2bf(Wo[r*64 + o]);
    }
    if (t < 80){
        bcoA[t] = (t < 64) ? bV[t]      : bEG[t-64];
        bcoB[t] = (t < 64) ? bV[64 + t] : bEG[16 + t-64];
    }
}

// ---------------------------------------------------------------------------
// k_proj<PASS>: fused LayerNorm + [128,64]@[64,80] bf16 MFMA + coalesced store.
// (unchanged from validated round-4 kernel)
// ---------------------------------------------------------------------------
template<int PASS>
__global__ __launch_bounds__(256) void k_proj(
    const float* __restrict__ e, const float* __restrict__ lns, const float* __restrict__ lnb,
    const unsigned short* __restrict__ Wt, const float* __restrict__ bco,
    unsigned short* __restrict__ Vdst, float* __restrict__ Sdst, float* __restrict__ Gdst)
{
    __shared__ unsigned short Alds[128*72];
    __shared__ unsigned short Wlds[80*72];
    __shared__ float bcs[80];
    const int tid = threadIdx.x;
    const int x0 = blockIdx.x * 128;
    const int y  = blockIdx.y;
    const int b  = blockIdx.z;
    const int z8 = b * 8;

    for (int c = tid; c < 640; c += 256){       // 640 chunks of 8 bf16
        int n = c >> 3, k8 = (c & 7) * 8;
        short8 v = *(const short8*)&Wt[c*8];
        *(short8*)&Wlds[n*72 + k8] = v;
    }
    if (tid < 80) bcs[tid] = bco[tid];

    const int lq = tid & 3;
    float scv[16], bsv[16];
    #pragma unroll
    for (int j = 0; j < 4; ++j){
        float4 s4 = *(const float4*)&lns[lq*16 + j*4];
        float4 b4 = *(const float4*)&lnb[lq*16 + j*4];
        scv[j*4+0]=s4.x; scv[j*4+1]=s4.y; scv[j*4+2]=s4.z; scv[j*4+3]=s4.w;
        bsv[j*4+0]=b4.x; bsv[j*4+1]=b4.y; bsv[j*4+2]=b4.z; bsv[j*4+3]=b4.w;
    }
    #pragma unroll
    for (int p = 0; p < 2; ++p){
        int lrow = p*64 + (tid >> 2);
        size_t gbase;
        if (PASS == 0) gbase = (((size_t)(b*NI + y)) * NI + x0 + lrow) * NE + lq*16;
        else           gbase = (((size_t)(b*NI + x0 + lrow)) * NI + y) * NE + lq*16;
        float xs[16];
        #pragma unroll
        for (int j = 0; j < 4; ++j){
            float4 x4 = *(const float4*)&e[gbase + j*4];
            xs[j*4+0]=x4.x; xs[j*4+1]=x4.y; xs[j*4+2]=x4.z; xs[j*4+3]=x4.w;
        }
        float s = 0.f, sq = 0.f;
        #pragma unroll
        for (int j = 0; j < 16; ++j){ s += xs[j]; sq += xs[j]*xs[j]; }
        s  += __shfl_xor(s, 1, 64);  s  += __shfl_xor(s, 2, 64);
        sq += __shfl_xor(sq, 1, 64); sq += __shfl_xor(sq, 2, 64);
        float mu = s * (1.f/64.f);
        float var = sq * (1.f/64.f) - mu*mu;
        float rs = rsqrtf(var + 1e-5f);
        short8 o0, o1;
        #pragma unroll
        for (int j = 0; j < 8; ++j){
            o0[j] = (short)f2bf((xs[j]   - mu)*rs*scv[j]   + bsv[j]);
            o1[j] = (short)f2bf((xs[j+8] - mu)*rs*scv[j+8] + bsv[j+8]);
        }
        *(short8*)&Alds[lrow*72 + lq*16]     = o0;
        *(short8*)&Alds[lrow*72 + lq*16 + 8] = o1;
    }
    __syncthreads();

    const int w = tid >> 6, l = tid & 63;
    const int lr = l & 15, lk = (l >> 4) * 8;
    floatx4 acc[2][5];
    #pragma unroll
    for (int mf = 0; mf < 2; ++mf)
        #pragma unroll
        for (int nf = 0; nf < 5; ++nf)
            acc[mf][nf] = (floatx4){0.f,0.f,0.f,0.f};

    #pragma unroll
    for (int ks = 0; ks < 2; ++ks){
        int kk = ks*32 + lk;
        short8 a0 = *(const short8*)&Alds[(w*32 +  0 + lr)*72 + kk];
        short8 a1 = *(const short8*)&Alds[(w*32 + 16 + lr)*72 + kk];
        #pragma unroll
        for (int nf = 0; nf < 5; ++nf){
            short8 bfr = *(const short8*)&Wlds[(nf*16 + lr)*72 + kk];
            acc[0][nf] = __builtin_amdgcn_mfma_f32_16x16x32_bf16(a0, bfr, acc[0][nf], 0, 0, 0);
            acc[1][nf] = __builtin_amdgcn_mfma_f32_16x16x32_bf16(a1, bfr, acc[1][nf], 0, 0, 0);
        }
    }

    const int rowoff = (l >> 4) * 4;
    #pragma unroll
    for (int mf = 0; mf < 2; ++mf){
        const int bl = x0 + w*32 + mf*16 + rowoff;
        #pragma unroll
        for (int nf = 0; nf < 4; ++nf){
            int ca = nf*16 + lr;
            int dd = ca >> 3, h = ca & 7;
            float bia = bcs[ca];
            US4 v;
            v.x = f2bf(acc[mf][nf][0] + bia);
            v.y = f2bf(acc[mf][nf][1] + bia);
            v.z = f2bf(acc[mf][nf][2] + bia);
            v.w = f2bf(acc[mf][nf][3] + bia);
            *(US4*)&Vdst[(size_t)(z8 + h)*VPLANE_E + (size_t)(y*8 + dd)*KPAD + bl] = v;
        }
        {
            float bia = bcs[64 + lr];
            int h = lr & 7;
            float* dst = (lr < 8) ? Sdst : Gdst;
            float4 v4 = make_float4(acc[mf][4][0] + bia, acc[mf][4][1] + bia,
                                    acc[mf][4][2] + bia, acc[mf][4][3] + bia);
            *(float4*)&dst[(size_t)(z8 + h)*NNI + (size_t)y*NI + bl] = v4;
        }
    }
}

// ---------------------------------------------------------------------------
// k_sm: row softmax over contiguous 384 + sigmoid gate -> bf16 A plane [392]
// (unchanged from validated round-3 kernel)
// ---------------------------------------------------------------------------
__global__ __launch_bounds__(256) void k_sm(
    const float* __restrict__ S, const float* __restrict__ G,
    const float* __restrict__ mask, unsigned short* __restrict__ Abf, int use_mask)
{
    const int tid = threadIdx.x, w = tid >> 6, lane = tid & 63;
    const int R = blockIdx.x * 4 + w;
    const size_t sbase = (size_t)R * NI;
    const int bh = R / NI, row = R - bh*NI;

    float sv[6], gv[6];
    float m = -1e30f;
    if (use_mask){
        const int b = R / (NH*NI);
        const size_t mbase = ((size_t)b * NI + row) * NI;
        #pragma unroll
        for (int q = 0; q < 6; ++q){
            int k = lane + q*64;
            float mk = mask[mbase + k];
            sv[q] = S[sbase + k] + mk;
            gv[q] = G[sbase + k] + mk;
            m = fmaxf(m, sv[q]);
        }
    } else {
        #pragma unroll
        for (int q = 0; q < 6; ++q){
            int k = lane + q*64;
            sv[q] = S[sbase + k];
            gv[q] = G[sbase + k];
            m = fmaxf(m, sv[q]);
        }
    }
    m = wave_max(m);
    float ssum = 0.f;
    #pragma unroll
    for (int q = 0; q < 6; ++q){ sv[q] = expf(sv[q] - m); ssum += sv[q]; }
    ssum = wave_sum(ssum);
    float inv = 1.f / ssum;
    unsigned short* dst = Abf + (size_t)bh * APLANE_E + (size_t)row * KPAD;
    #pragma unroll
    for (int q = 0; q < 6; ++q){
        float sig = 1.f / (1.f + expf(-gv[q]));
        dst[lane + q*64] = f2bf(sv[q] * inv * sig);
    }
}

// ---------------------------------------------------------------------------
// k_gemm v4: C[384,3072] = A[384,384] @ B^T (B stored [n][k]), bf16 MFMA.
// Block tile 128x256, 512 threads = 2x4 waves, wave tile 64x64 (acc 4x4).
// T3+T4 2-phase pipeline: double-buffered LDS, stage(t+1) issued BEFORE
// compute(t), counted s_waitcnt vmcnt(6) (never 0 in main loop), raw
// s_barrier (no compiler vmcnt(0) drain). Staging via global_load_lds w=16
// into linear LDS, XOR chunk-swizzle applied on the GLOBAL source address;
// ds_read_b128 applies the same XOR (<=2-way bank aliasing = free).
// 1D grid 1152, bijective XCD swizzle (144 blocks = 4 whole planes per XCD).
// ---------------------------------------------------------------------------
__global__ __launch_bounds__(512, 1) void k_gemm(
    const unsigned short* __restrict__ AinP, const unsigned short* __restrict__ AoutP,
    const unsigned short* __restrict__ VinP, const unsigned short* __restrict__ VoutP,
    unsigned short* __restrict__ VaIn, unsigned short* __restrict__ VaOut)
{
    __shared__ unsigned short Al[2][128*64];   // 2 x 16 KB
    __shared__ unsigned short Bl[2][256*64];   // 2 x 32 KB  (total 96 KB)
    const int tid = threadIdx.x;

    // XCD-aware bijective swizzle: 1152 blocks = 8 XCDs x 144
    const int L = blockIdx.x;
    const int W = (L & 7) * 144 + (L >> 3);
    const int nt = W % 12;
    const int mt = (W / 12) % 3;
    const int z  = W / 36;
    const int dir = z >> 4, bh = z & 15;
    const unsigned short* Ap = (dir ? AoutP : AinP) + (size_t)bh * APLANE_E;
    const unsigned short* Bp = (dir ? VoutP : VinP) + (size_t)bh * VPLANE_E;
    unsigned short* Cp = (dir ? VaOut : VaIn) + (size_t)bh * PLANE;
    const int m0 = mt*128, n0 = nt*256;

    const int w = tid >> 6, l = tid & 63;
    const int lr = l & 15, lk4 = l >> 4;
    const int wr = w >> 2, wc = w & 3;          // 2 x 4 wave grid

    // staging lane geometry: lane l covers (row_in_inst = l>>3, phys chunk = l&7)
    const int srow8  = l >> 3;                  // 0..7
    const int schunk = (l & 7) ^ srow8;         // logical chunk to fetch

    // per-wave staging: A insts {2w, 2w+1} of 16; B insts {4w..4w+3} of 32
    // -> 6 global_load_lds per wave per K-tile
    auto STAGE = [&](int buf, int kb){
        const int k0 = kb*64;
        #pragma unroll
        for (int t2 = 0; t2 < 2; ++t2){
            int inst = w*2 + t2;
            gl_lds16(&Ap[(size_t)(m0 + inst*8 + srow8)*KPAD + k0 + schunk*8],
                     &Al[buf][inst*512]);
        }
        #pragma unroll
        for (int t4 = 0; t4 < 4; ++t4){
            int inst = w*4 + t4;
            gl_lds16(&Bp[(size_t)(n0 + inst*8 + srow8)*KPAD + k0 + schunk*8],
                     &Bl[buf][inst*512]);
        }
    };

    floatx4 acc[4][4];
    #pragma unroll
    for (int mf = 0; mf < 4; ++mf)
        #pragma unroll
        for (int nf = 0; nf < 4; ++nf)
            acc[mf][nf] = (floatx4){0.f,0.f,0.f,0.f};

    STAGE(0, 0);                                 // prologue

    #pragma unroll
    for (int t = 0; t < 6; ++t){
        const int buf = t & 1;
        if (t < 5){
            STAGE(buf ^ 1, t + 1);               // issue next tile FIRST
            asm volatile("s_waitcnt vmcnt(6)" ::: "memory");   // tile-t landed (wave-local)
        } else {
            asm volatile("s_waitcnt vmcnt(0)" ::: "memory");
        }
        asm volatile("s_barrier" ::: "memory");  // block-wide: tile-t resident
        #pragma unroll
        for (int ks = 0; ks < 2; ++ks){
            const int cx = ((ks*4 + lk4) ^ (lr & 7)) * 8;   // swizzled chunk (shorts)
            short8 a[4], b[4];
            #pragma unroll
            for (int mf = 0; mf < 4; ++mf)
                a[mf] = *(const short8*)&Al[buf][(wr*64 + mf*16 + lr)*64 + cx];
            #pragma unroll
            for (int nf = 0; nf < 4; ++nf)
                b[nf] = *(const short8*)&Bl[buf][(wc*64 + nf*16 + lr)*64 + cx];
            #pragma unroll
            for (int mf = 0; mf < 4; ++mf)
                #pragma unroll
                for (int nf = 0; nf < 4; ++nf)
                    acc[mf][nf] = __builtin_amdgcn_mfma_f32_16x16x32_bf16(a[mf], b[nf], acc[mf][nf], 0, 0, 0);
        }
        if (t < 5)
            asm volatile("s_barrier" ::: "memory");  // all reads of buf done before overwrite
    }

    const int rowoff = lk4 * 4;
    #pragma unroll
    for (int mf = 0; mf < 4; ++mf)
        #pragma unroll
        for (int q = 0; q < 4; ++q){
            int i = m0 + wr*64 + mf*16 + rowoff + q;
            #pragma unroll
            for (int nf = 0; nf < 4; ++nf){
                int n = n0 + wc*64 + nf*16 + lr;
                Cp[(size_t)i*MCOLS + n] = f2bf(acc[mf][nf][q]);
            }
        }
}

// ---------------------------------------------------------------------------
// k_f2: epilogue GEMM via MFMA, no A-staging.
// (unchanged from validated round-5 kernel)
// ---------------------------------------------------------------------------
__global__ __launch_bounds__(192) void k_f2(
    const unsigned short* __restrict__ Vain, const unsigned short* __restrict__ Vaout,
    const unsigned short* __restrict__ WoT, const float* __restrict__ bO,
    float* __restrict__ out)
{
    __shared__ unsigned short wl[64*136];
    const int tid = threadIdx.x;
    const int jt = blockIdx.x, i = blockIdx.y, b = blockIdx.z;

    for (int cc = tid; cc < 1024; cc += 192){     // stage WoT [64][128] -> [64][136]
        int o = cc >> 4, k8 = (cc & 15) * 8;
        short8 v = *(const short8*)&WoT[cc*8];
        *(short8*)&wl[o*136 + k8] = v;
    }

    const int w = tid >> 6, l = tid & 63;
    const int lr = l & 15, lk = (l >> 4) * 8;
    const int j0 = jt*192 + w*64;

    float bias[4];
    #pragma unroll
    for (int nf = 0; nf < 4; ++nf) bias[nf] = bO[nf*16 + lr];

    __syncthreads();

    short8 bfr[4][4];
    #pragma unroll
    for (int ks = 0; ks < 4; ++ks)
        #pragma unroll
        for (int nf = 0; nf < 4; ++nf)
            bfr[ks][nf] = *(const short8*)&wl[(nf*16 + lr)*136 + ks*32 + lk];

    floatx4 acc[4][4];
    #pragma unroll
    for (int mf = 0; mf < 4; ++mf)
        #pragma unroll
        for (int nf = 0; nf < 4; ++nf)
            acc[mf][nf] = (floatx4){0.f,0.f,0.f,0.f};

    const int p_lane = (l >> 4);
    #pragma unroll
    for (int mf = 0; mf < 4; ++mf){
        int j = j0 + mf*16 + lr;
        short8 a[4];
        #pragma unroll
        for (int ks = 0; ks < 4; ++ks){
            int p = ks*4 + p_lane;
            const unsigned short* src = (p >= 8) ? Vaout : Vain;
            int h = p & 7;
            a[ks] = *(const short8*)&src[(size_t)(b*8 + h)*PLANE + (size_t)i*MCOLS + (size_t)j*8];
        }
        #pragma unroll
        for (int ks = 0; ks < 4; ++ks)
            #pragma unroll
            for (int nf = 0; nf < 4; ++nf)
                acc[mf][nf] = __builtin_amdgcn_mfma_f32_16x16x32_bf16(a[ks], bfr[ks][nf], acc[mf][nf], 0, 0, 0);
    }

    const int rowoff = (l >> 4) * 4;
    const size_t obase = ((size_t)(b*NI + i)) * NI;
    #pragma unroll
    for (int mf = 0; mf < 4; ++mf)
        #pragma unroll
        for (int q = 0; q < 4; ++q){
            int j = j0 + mf*16 + rowoff + q;
            #pragma unroll
            for (int nf = 0; nf < 4; ++nf)
                out[(obase + j)*NE + nf*16 + lr] = acc[mf][nf][q] + bias[nf];
        }
}

// ---------------------------------------------------------------------------
extern "C" void kernel_launch(void* const* d_in, const int* in_sizes, int n_in,
                              void* d_out, int out_size, void* d_ws, size_t ws_size,
                              hipStream_t stream)
{
    const float* e    = (const float*)d_in[0];
    const float* mask = (const float*)d_in[1];
    const float* lns  = (const float*)d_in[2];
    const float* lnb  = (const float*)d_in[3];
    const float* Wv   = (const float*)d_in[4];
    const float* bV   = (const float*)d_in[5];
    const float* Weg  = (const float*)d_in[6];
    const float* bEG  = (const float*)d_in[7];
    const float* Wo   = (const float*)d_in[8];
    const float* bO   = (const float*)d_in[9];

    unsigned short* VinP  = (unsigned short*)d_ws;
    unsigned short* VoutP = VinP  + (size_t)16 * VPLANE_E;
    unsigned short* AinP  = VoutP + (size_t)16 * VPLANE_E;
    unsigned short* AoutP = AinP  + (size_t)16 * APLANE_E;
    unsigned short* WtA   = AoutP + (size_t)16 * APLANE_E;
    unsigned short* WtB   = WtA + 5120;
    unsigned short* WoT   = WtB + 5120;
    float* bcoA = (float*)(WoT + 8192);
    float* bcoB = bcoA + 80;
    float* Sin  = bcoB + 80;
    float* Gin  = Sin  + (size_t)16 * NNI;
    float* Sout = Gin  + (size_t)16 * NNI;
    float* Gout = Sout + (size_t)16 * NNI;
    unsigned short* VaIn  = (unsigned short*)Sin;           // alias: S/G dead by k_gemm
    unsigned short* VaOut = (unsigned short*)(Gout + (size_t)16 * NNI);

    k_w<<<1, 256, 0, stream>>>(Wv, Weg, bV, bEG, Wo, WtA, WtB, bcoA, bcoB, WoT);
    k_proj<0><<<dim3(3, NI, NB), 256, 0, stream>>>(e, lns, lnb, WtA, bcoA, VinP,  Sin,  Gin);
    k_proj<1><<<dim3(3, NI, NB), 256, 0, stream>>>(e, lns, lnb, WtB, bcoB, VoutP, Sout, Gout);
    k_sm  <<<(16*NI)/4, 256, 0, stream>>>(Sin,  Gin,  mask, AinP,  1);
    k_sm  <<<(16*NI)/4, 256, 0, stream>>>(Sout, Gout, mask, AoutP, 0);
    k_gemm<<<dim3(1152), 512, 0, stream>>>(AinP, AoutP, VinP, VoutP, VaIn, VaOut);
    k_f2  <<<dim3(2, NI, NB), 192, 0, stream>>>(VaIn, VaOut, WoT, bO, (float*)d_out);
}

// Round 9
// 180.728 us; speedup vs baseline: 1.0250x; 1.0250x over previous
//
#include <hip/hip_runtime.h>
#include <hip/hip_bf16.h>

// Problem constants
#define NB 2
#define NI 384
#define NE 64
#define NH 8
#define NNI (NI*NI)                 // 147456
#define NROWS (NB*NNI)              // 294912
#define MCOLS (NI*8)                // 3072
#define PLANE ((size_t)NI*MCOLS)    // 1179648 elems per (b,h) Va plane
#define KPAD 392                    // padded K stride for bf16 planes (784 B rows, 16B-aligned)
#define VPLANE_E ((size_t)MCOLS*KPAD)   // 1204224 elems per V plane
#define APLANE_E ((size_t)NI*KPAD)      // 150528 elems per A plane

typedef __attribute__((ext_vector_type(8))) short short8;
typedef __attribute__((ext_vector_type(4))) float floatx4;

struct alignas(8) US4 { unsigned short x, y, z, w; };

__device__ __forceinline__ float bf2f(unsigned short u){ return __uint_as_float(((unsigned)u) << 16); }
__device__ __forceinline__ unsigned short f2bf(float f){
    unsigned x = __float_as_uint(f);
    x += 0x7fffu + ((x >> 16) & 1u);          // round-to-nearest-even
    return (unsigned short)(x >> 16);
}

__device__ __forceinline__ float wave_sum(float v){
    #pragma unroll
    for (int m = 32; m > 0; m >>= 1) v += __shfl_xor(v, m, 64);
    return v;
}
__device__ __forceinline__ float wave_max(float v){
    #pragma unroll
    for (int m = 32; m > 0; m >>= 1) v = fmaxf(v, __shfl_xor(v, m, 64));
    return v;
}

// async global->LDS, 16B per lane; LDS dest is wave-uniform base + lane*16
__device__ __forceinline__ void gl_lds16(const unsigned short* g, unsigned short* l){
    __builtin_amdgcn_global_load_lds(
        (__attribute__((address_space(1))) void*)(g),
        (__attribute__((address_space(3))) void*)(l), 16, 0, 0);
}

// ---------------------------------------------------------------------------
// k_w: weight prep (unchanged from validated round-5 kernel).
// ---------------------------------------------------------------------------
__global__ __launch_bounds__(256) void k_w(
    const float* __restrict__ Wv, const float* __restrict__ Weg,
    const float* __restrict__ bV, const float* __restrict__ bEG,
    const float* __restrict__ Wo,
    unsigned short* __restrict__ WtA, unsigned short* __restrict__ WtB,
    float* __restrict__ bcoA, float* __restrict__ bcoB,
    unsigned short* __restrict__ WoT)
{
    const int t = threadIdx.x;
    for (int idx = t; idx < 5120; idx += 256){
        int n = idx >> 6, k = idx & 63;
        WtA[idx] = f2bf((n < 64) ? Wv[k*128 + n]      : Weg[k*32 + (n-64)]);
        WtB[idx] = f2bf((n < 64) ? Wv[k*128 + 64 + n] : Weg[k*32 + 16 + (n-64)]);
    }
    for (int idx = t; idx < 8192; idx += 256){
        int o = idx >> 7, c = idx & 127;
        int r = (c & 7)*16 + (c >> 3);
        WoT[idx] = f2bf(Wo[r*64 + o]);
    }
    if (t < 80){
        bcoA[t] = (t < 64) ? bV[t]      : bEG[t-64];
        bcoB[t] = (t < 64) ? bV[64 + t] : bEG[16 + t-64];
    }
}

// ---------------------------------------------------------------------------
// k_proj<PASS>: fused LayerNorm + [128,64]@[64,80] bf16 MFMA + coalesced store.
// (unchanged from validated round-4 kernel)
// ---------------------------------------------------------------------------
template<int PASS>
__global__ __launch_bounds__(256) void k_proj(
    const float* __restrict__ e, const float* __restrict__ lns, const float* __restrict__ lnb,
    const unsigned short* __restrict__ Wt, const float* __restrict__ bco,
    unsigned short* __restrict__ Vdst, float* __restrict__ Sdst, float* __restrict__ Gdst)
{
    __shared__ unsigned short Alds[128*72];
    __shared__ unsigned short Wlds[80*72];
    __shared__ float bcs[80];
    const int tid = threadIdx.x;
    const int x0 = blockIdx.x * 128;
    const int y  = blockIdx.y;
    const int b  = blockIdx.z;
    const int z8 = b * 8;

    for (int c = tid; c < 640; c += 256){       // 640 chunks of 8 bf16
        int n = c >> 3, k8 = (c & 7) * 8;
        short8 v = *(const short8*)&Wt[c*8];
        *(short8*)&Wlds[n*72 + k8] = v;
    }
    if (tid < 80) bcs[tid] = bco[tid];

    const int lq = tid & 3;
    float scv[16], bsv[16];
    #pragma unroll
    for (int j = 0; j < 4; ++j){
        float4 s4 = *(const float4*)&lns[lq*16 + j*4];
        float4 b4 = *(const float4*)&lnb[lq*16 + j*4];
        scv[j*4+0]=s4.x; scv[j*4+1]=s4.y; scv[j*4+2]=s4.z; scv[j*4+3]=s4.w;
        bsv[j*4+0]=b4.x; bsv[j*4+1]=b4.y; bsv[j*4+2]=b4.z; bsv[j*4+3]=b4.w;
    }
    #pragma unroll
    for (int p = 0; p < 2; ++p){
        int lrow = p*64 + (tid >> 2);
        size_t gbase;
        if (PASS == 0) gbase = (((size_t)(b*NI + y)) * NI + x0 + lrow) * NE + lq*16;
        else           gbase = (((size_t)(b*NI + x0 + lrow)) * NI + y) * NE + lq*16;
        float xs[16];
        #pragma unroll
        for (int j = 0; j < 4; ++j){
            float4 x4 = *(const float4*)&e[gbase + j*4];
            xs[j*4+0]=x4.x; xs[j*4+1]=x4.y; xs[j*4+2]=x4.z; xs[j*4+3]=x4.w;
        }
        float s = 0.f, sq = 0.f;
        #pragma unroll
        for (int j = 0; j < 16; ++j){ s += xs[j]; sq += xs[j]*xs[j]; }
        s  += __shfl_xor(s, 1, 64);  s  += __shfl_xor(s, 2, 64);
        sq += __shfl_xor(sq, 1, 64); sq += __shfl_xor(sq, 2, 64);
        float mu = s * (1.f/64.f);
        float var = sq * (1.f/64.f) - mu*mu;
        float rs = rsqrtf(var + 1e-5f);
        short8 o0, o1;
        #pragma unroll
        for (int j = 0; j < 8; ++j){
            o0[j] = (short)f2bf((xs[j]   - mu)*rs*scv[j]   + bsv[j]);
            o1[j] = (short)f2bf((xs[j+8] - mu)*rs*scv[j+8] + bsv[j+8]);
        }
        *(short8*)&Alds[lrow*72 + lq*16]     = o0;
        *(short8*)&Alds[lrow*72 + lq*16 + 8] = o1;
    }
    __syncthreads();

    const int w = tid >> 6, l = tid & 63;
    const int lr = l & 15, lk = (l >> 4) * 8;
    floatx4 acc[2][5];
    #pragma unroll
    for (int mf = 0; mf < 2; ++mf)
        #pragma unroll
        for (int nf = 0; nf < 5; ++nf)
            acc[mf][nf] = (floatx4){0.f,0.f,0.f,0.f};

    #pragma unroll
    for (int ks = 0; ks < 2; ++ks){
        int kk = ks*32 + lk;
        short8 a0 = *(const short8*)&Alds[(w*32 +  0 + lr)*72 + kk];
        short8 a1 = *(const short8*)&Alds[(w*32 + 16 + lr)*72 + kk];
        #pragma unroll
        for (int nf = 0; nf < 5; ++nf){
            short8 bfr = *(const short8*)&Wlds[(nf*16 + lr)*72 + kk];
            acc[0][nf] = __builtin_amdgcn_mfma_f32_16x16x32_bf16(a0, bfr, acc[0][nf], 0, 0, 0);
            acc[1][nf] = __builtin_amdgcn_mfma_f32_16x16x32_bf16(a1, bfr, acc[1][nf], 0, 0, 0);
        }
    }

    const int rowoff = (l >> 4) * 4;
    #pragma unroll
    for (int mf = 0; mf < 2; ++mf){
        const int bl = x0 + w*32 + mf*16 + rowoff;
        #pragma unroll
        for (int nf = 0; nf < 4; ++nf){
            int ca = nf*16 + lr;
            int dd = ca >> 3, h = ca & 7;
            float bia = bcs[ca];
            US4 v;
            v.x = f2bf(acc[mf][nf][0] + bia);
            v.y = f2bf(acc[mf][nf][1] + bia);
            v.z = f2bf(acc[mf][nf][2] + bia);
            v.w = f2bf(acc[mf][nf][3] + bia);
            *(US4*)&Vdst[(size_t)(z8 + h)*VPLANE_E + (size_t)(y*8 + dd)*KPAD + bl] = v;
        }
        {
            float bia = bcs[64 + lr];
            int h = lr & 7;
            float* dst = (lr < 8) ? Sdst : Gdst;
            float4 v4 = make_float4(acc[mf][4][0] + bia, acc[mf][4][1] + bia,
                                    acc[mf][4][2] + bia, acc[mf][4][3] + bia);
            *(float4*)&dst[(size_t)(z8 + h)*NNI + (size_t)y*NI + bl] = v4;
        }
    }
}

// ---------------------------------------------------------------------------
// k_sm: row softmax over contiguous 384 + sigmoid gate -> bf16 A plane [392]
// (unchanged from validated round-3 kernel)
// ---------------------------------------------------------------------------
__global__ __launch_bounds__(256) void k_sm(
    const float* __restrict__ S, const float* __restrict__ G,
    const float* __restrict__ mask, unsigned short* __restrict__ Abf, int use_mask)
{
    const int tid = threadIdx.x, w = tid >> 6, lane = tid & 63;
    const int R = blockIdx.x * 4 + w;
    const size_t sbase = (size_t)R * NI;
    const int bh = R / NI, row = R - bh*NI;

    float sv[6], gv[6];
    float m = -1e30f;
    if (use_mask){
        const int b = R / (NH*NI);
        const size_t mbase = ((size_t)b * NI + row) * NI;
        #pragma unroll
        for (int q = 0; q < 6; ++q){
            int k = lane + q*64;
            float mk = mask[mbase + k];
            sv[q] = S[sbase + k] + mk;
            gv[q] = G[sbase + k] + mk;
            m = fmaxf(m, sv[q]);
        }
    } else {
        #pragma unroll
        for (int q = 0; q < 6; ++q){
            int k = lane + q*64;
            sv[q] = S[sbase + k];
            gv[q] = G[sbase + k];
            m = fmaxf(m, sv[q]);
        }
    }
    m = wave_max(m);
    float ssum = 0.f;
    #pragma unroll
    for (int q = 0; q < 6; ++q){ sv[q] = expf(sv[q] - m); ssum += sv[q]; }
    ssum = wave_sum(ssum);
    float inv = 1.f / ssum;
    unsigned short* dst = Abf + (size_t)bh * APLANE_E + (size_t)row * KPAD;
    #pragma unroll
    for (int q = 0; q < 6; ++q){
        float sig = 1.f / (1.f + expf(-gv[q]));
        dst[lane + q*64] = f2bf(sv[q] * inv * sig);
    }
}

// ---------------------------------------------------------------------------
// k_gemm v5: C[384,3072] = A[384,384] @ B^T (B stored [n][k]), bf16 MFMA.
// R7 geometry (256 thr, block 128x256, wave 64x128, 2 blocks/CU) + T3/T4
// pipeline: BK=32 double-buffered LDS (2x24 KB = 48 KB, same as R7), per-wave
// 6 global_load_lds per K-tile, counted s_waitcnt vmcnt(6) (never 0 in-loop),
// raw s_barrier (no compiler vmcnt(0) drain). Loads for tile t+1 stay in
// flight across compute(t). XOR chunk-swizzle on the GLOBAL source address;
// ds_read_b128 applies the inverse XOR -> 2-way bank aliasing (free).
// 1D grid 1152, bijective XCD swizzle (144 blocks = 4 whole planes per XCD).
// ---------------------------------------------------------------------------
__global__ __launch_bounds__(256, 2) void k_gemm(
    const unsigned short* __restrict__ AinP, const unsigned short* __restrict__ AoutP,
    const unsigned short* __restrict__ VinP, const unsigned short* __restrict__ VoutP,
    unsigned short* __restrict__ VaIn, unsigned short* __restrict__ VaOut)
{
    __shared__ unsigned short Al[2][128*32];   // 2 x 8 KB  (BK=32: 64 B rows)
    __shared__ unsigned short Bl[2][256*32];   // 2 x 16 KB (total 48 KB)
    const int tid = threadIdx.x;

    // XCD-aware bijective swizzle: 1152 blocks = 8 XCDs x 144
    const int L = blockIdx.x;
    const int W = (L & 7) * 144 + (L >> 3);
    const int nt = W % 12;
    const int mt = (W / 12) % 3;
    const int z  = W / 36;
    const int dir = z >> 4, bh = z & 15;
    const unsigned short* Ap = (dir ? AoutP : AinP) + (size_t)bh * APLANE_E;
    const unsigned short* Bp = (dir ? VoutP : VinP) + (size_t)bh * VPLANE_E;
    unsigned short* Cp = (dir ? VaOut : VaIn) + (size_t)bh * PLANE;
    const int m0 = mt*128, n0 = nt*256;

    const int w = tid >> 6, l = tid & 63;
    const int lr = l & 15, lk4 = l >> 4;
    const int wr = w >> 1, wc = w & 1;          // 2 x 2 wave grid, wave tile 64x128

    // staging lane geometry: inst = 16 rows x 64 B; lane l covers
    // (row_in_inst = l>>2, phys chunk = l&3); logical chunk fetched is XOR'd
    const int srow   = l >> 2;                              // 0..15
    const int schunk = (l & 3) ^ (srow & 3) ^ ((srow >> 2) & 3);

    // per-wave staging: A insts {2w, 2w+1} of 8; B insts {4w..4w+3} of 16
    // -> 6 global_load_lds per wave per K-tile
    auto STAGE = [&](int buf, int kb){
        const int k0 = kb*32;
        #pragma unroll
        for (int t2 = 0; t2 < 2; ++t2){
            int inst = w*2 + t2;
            gl_lds16(&Ap[(size_t)(m0 + inst*16 + srow)*KPAD + k0 + schunk*8],
                     &Al[buf][inst*512]);
        }
        #pragma unroll
        for (int t4 = 0; t4 < 4; ++t4){
            int inst = w*4 + t4;
            gl_lds16(&Bp[(size_t)(n0 + inst*16 + srow)*KPAD + k0 + schunk*8],
                     &Bl[buf][inst*512]);
        }
    };

    floatx4 acc[4][8];
    #pragma unroll
    for (int mf = 0; mf < 4; ++mf)
        #pragma unroll
        for (int nf = 0; nf < 8; ++nf)
            acc[mf][nf] = (floatx4){0.f,0.f,0.f,0.f};

    // read-side swizzled chunk: logical chunk = lk4 (k-slice), row_in_inst = lr
    const int rchunk = (lk4 ^ (lr & 3) ^ ((lr >> 2) & 3)) * 8;   // shorts

    STAGE(0, 0);                                 // prologue

    #pragma unroll
    for (int t = 0; t < 12; ++t){
        const int buf = t & 1;
        if (t < 11){
            STAGE(buf ^ 1, t + 1);               // issue next tile FIRST
            asm volatile("s_waitcnt vmcnt(6)" ::: "memory");   // tile-t landed (this wave)
        } else {
            asm volatile("s_waitcnt vmcnt(0)" ::: "memory");
        }
        __builtin_amdgcn_s_barrier();            // block-wide: tile-t resident
        {
            short8 a[4], b[8];
            #pragma unroll
            for (int mf = 0; mf < 4; ++mf)
                a[mf] = *(const short8*)&Al[buf][(wr*4 + mf)*512 + lr*32 + rchunk];
            #pragma unroll
            for (int nf = 0; nf < 8; ++nf)
                b[nf] = *(const short8*)&Bl[buf][(wc*8 + nf)*512 + lr*32 + rchunk];
            #pragma unroll
            for (int mf = 0; mf < 4; ++mf)
                #pragma unroll
                for (int nf = 0; nf < 8; ++nf)
                    acc[mf][nf] = __builtin_amdgcn_mfma_f32_16x16x32_bf16(a[mf], b[nf], acc[mf][nf], 0, 0, 0);
        }
        if (t < 11)
            __builtin_amdgcn_s_barrier();        // all reads of buf done before overwrite
    }

    const int rowoff = lk4 * 4;
    #pragma unroll
    for (int mf = 0; mf < 4; ++mf)
        #pragma unroll
        for (int q = 0; q < 4; ++q){
            int i = m0 + wr*64 + mf*16 + rowoff + q;
            #pragma unroll
            for (int nf = 0; nf < 8; ++nf){
                int n = n0 + wc*128 + nf*16 + lr;
                Cp[(size_t)i*MCOLS + n] = f2bf(acc[mf][nf][q]);
            }
        }
}

// ---------------------------------------------------------------------------
// k_f2: epilogue GEMM via MFMA, no A-staging.
// (unchanged from validated round-5 kernel)
// ---------------------------------------------------------------------------
__global__ __launch_bounds__(192) void k_f2(
    const unsigned short* __restrict__ Vain, const unsigned short* __restrict__ Vaout,
    const unsigned short* __restrict__ WoT, const float* __restrict__ bO,
    float* __restrict__ out)
{
    __shared__ unsigned short wl[64*136];
    const int tid = threadIdx.x;
    const int jt = blockIdx.x, i = blockIdx.y, b = blockIdx.z;

    for (int cc = tid; cc < 1024; cc += 192){     // stage WoT [64][128] -> [64][136]
        int o = cc >> 4, k8 = (cc & 15) * 8;
        short8 v = *(const short8*)&WoT[cc*8];
        *(short8*)&wl[o*136 + k8] = v;
    }

    const int w = tid >> 6, l = tid & 63;
    const int lr = l & 15, lk = (l >> 4) * 8;
    const int j0 = jt*192 + w*64;

    float bias[4];
    #pragma unroll
    for (int nf = 0; nf < 4; ++nf) bias[nf] = bO[nf*16 + lr];

    __syncthreads();

    short8 bfr[4][4];
    #pragma unroll
    for (int ks = 0; ks < 4; ++ks)
        #pragma unroll
        for (int nf = 0; nf < 4; ++nf)
            bfr[ks][nf] = *(const short8*)&wl[(nf*16 + lr)*136 + ks*32 + lk];

    floatx4 acc[4][4];
    #pragma unroll
    for (int mf = 0; mf < 4; ++mf)
        #pragma unroll
        for (int nf = 0; nf < 4; ++nf)
            acc[mf][nf] = (floatx4){0.f,0.f,0.f,0.f};

    const int p_lane = (l >> 4);
    #pragma unroll
    for (int mf = 0; mf < 4; ++mf){
        int j = j0 + mf*16 + lr;
        short8 a[4];
        #pragma unroll
        for (int ks = 0; ks < 4; ++ks){
            int p = ks*4 + p_lane;
            const unsigned short* src = (p >= 8) ? Vaout : Vain;
            int h = p & 7;
            a[ks] = *(const short8*)&src[(size_t)(b*8 + h)*PLANE + (size_t)i*MCOLS + (size_t)j*8];
        }
        #pragma unroll
        for (int ks = 0; ks < 4; ++ks)
            #pragma unroll
            for (int nf = 0; nf < 4; ++nf)
                acc[mf][nf] = __builtin_amdgcn_mfma_f32_16x16x32_bf16(a[ks], bfr[ks][nf], acc[mf][nf], 0, 0, 0);
    }

    const int rowoff = (l >> 4) * 4;
    const size_t obase = ((size_t)(b*NI + i)) * NI;
    #pragma unroll
    for (int mf = 0; mf < 4; ++mf)
        #pragma unroll
        for (int q = 0; q < 4; ++q){
            int j = j0 + mf*16 + rowoff + q;
            #pragma unroll
            for (int nf = 0; nf < 4; ++nf)
                out[(obase + j)*NE + nf*16 + lr] = acc[mf][nf][q] + bias[nf];
        }
}

// ---------------------------------------------------------------------------
extern "C" void kernel_launch(void* const* d_in, const int* in_sizes, int n_in,
                              void* d_out, int out_size, void* d_ws, size_t ws_size,
                              hipStream_t stream)
{
    const float* e    = (const float*)d_in[0];
    const float* mask = (const float*)d_in[1];
    const float* lns  = (const float*)d_in[2];
    const float* lnb  = (const float*)d_in[3];
    const float* Wv   = (const float*)d_in[4];
    const float* bV   = (const float*)d_in[5];
    const float* Weg  = (const float*)d_in[6];
    const float* bEG  = (const float*)d_in[7];
    const float* Wo   = (const float*)d_in[8];
    const float* bO   = (const float*)d_in[9];

    unsigned short* VinP  = (unsigned short*)d_ws;
    unsigned short* VoutP = VinP  + (size_t)16 * VPLANE_E;
    unsigned short* AinP  = VoutP + (size_t)16 * VPLANE_E;
    unsigned short* AoutP = AinP  + (size_t)16 * APLANE_E;
    unsigned short* WtA   = AoutP + (size_t)16 * APLANE_E;
    unsigned short* WtB   = WtA + 5120;
    unsigned short* WoT   = WtB + 5120;
    float* bcoA = (float*)(WoT + 8192);
    float* bcoB = bcoA + 80;
    float* Sin  = bcoB + 80;
    float* Gin  = Sin  + (size_t)16 * NNI;
    float* Sout = Gin  + (size_t)16 * NNI;
    float* Gout = Sout + (size_t)16 * NNI;
    unsigned short* VaIn  = (unsigned short*)Sin;           // alias: S/G dead by k_gemm
    unsigned short* VaOut = (unsigned short*)(Gout + (size_t)16 * NNI);

    k_w<<<1, 256, 0, stream>>>(Wv, Weg, bV, bEG, Wo, WtA, WtB, bcoA, bcoB, WoT);
    k_proj<0><<<dim3(3, NI, NB), 256, 0, stream>>>(e, lns, lnb, WtA, bcoA, VinP,  Sin,  Gin);
    k_proj<1><<<dim3(3, NI, NB), 256, 0, stream>>>(e, lns, lnb, WtB, bcoB, VoutP, Sout, Gout);
    k_sm  <<<(16*NI)/4, 256, 0, stream>>>(Sin,  Gin,  mask, AinP,  1);
    k_sm  <<<(16*NI)/4, 256, 0, stream>>>(Sout, Gout, mask, AoutP, 0);
    k_gemm<<<dim3(1152), 256, 0, stream>>>(AinP, AoutP, VinP, VoutP, VaIn, VaOut);
    k_f2  <<<dim3(2, NI, NB), 192, 0, stream>>>(VaIn, VaOut, WoT, bO, (float*)d_out);
}

// Round 10
// 167.532 us; speedup vs baseline: 1.1057x; 1.0788x over previous
//
#include <hip/hip_runtime.h>
#include <hip/hip_bf16.h>

// Problem constants
#define NB 2
#define NI 384
#define NE 64
#define NH 8
#define NNI (NI*NI)                 // 147456
#define NROWS (NB*NNI)              // 294912
#define MCOLS (NI*8)                // 3072
#define PLANE ((size_t)NI*MCOLS)    // 1179648 elems per (b,h) Va plane
#define KPAD 392                    // padded K stride for bf16 planes (784 B rows, 16B-aligned)
#define VPLANE_E ((size_t)MCOLS*KPAD)   // 1204224 elems per V plane
#define APLANE_E ((size_t)NI*KPAD)      // 150528 elems per A plane

typedef __attribute__((ext_vector_type(8))) short short8;
typedef __attribute__((ext_vector_type(4))) float floatx4;

struct alignas(8) US4 { unsigned short x, y, z, w; };

__device__ __forceinline__ float bf2f(unsigned short u){ return __uint_as_float(((unsigned)u) << 16); }
__device__ __forceinline__ unsigned short f2bf(float f){
    unsigned x = __float_as_uint(f);
    x += 0x7fffu + ((x >> 16) & 1u);          // round-to-nearest-even
    return (unsigned short)(x >> 16);
}

__device__ __forceinline__ float wave_sum(float v){
    #pragma unroll
    for (int m = 32; m > 0; m >>= 1) v += __shfl_xor(v, m, 64);
    return v;
}
__device__ __forceinline__ float wave_max(float v){
    #pragma unroll
    for (int m = 32; m > 0; m >>= 1) v = fmaxf(v, __shfl_xor(v, m, 64));
    return v;
}

// async global->LDS, 16B per lane; LDS dest is wave-uniform base + lane*16
__device__ __forceinline__ void gl_lds16(const unsigned short* g, unsigned short* l){
    __builtin_amdgcn_global_load_lds(
        (__attribute__((address_space(1))) void*)(g),
        (__attribute__((address_space(3))) void*)(l), 16, 0, 0);
}

// ---------------------------------------------------------------------------
// k_w: weight prep (unchanged from validated round-5 kernel).
// ---------------------------------------------------------------------------
__global__ __launch_bounds__(256) void k_w(
    const float* __restrict__ Wv, const float* __restrict__ Weg,
    const float* __restrict__ bV, const float* __restrict__ bEG,
    const float* __restrict__ Wo,
    unsigned short* __restrict__ WtA, unsigned short* __restrict__ WtB,
    float* __restrict__ bcoA, float* __restrict__ bcoB,
    unsigned short* __restrict__ WoT)
{
    const int t = threadIdx.x;
    for (int idx = t; idx < 5120; idx += 256){
        int n = idx >> 6, k = idx & 63;
        WtA[idx] = f2bf((n < 64) ? Wv[k*128 + n]      : Weg[k*32 + (n-64)]);
        WtB[idx] = f2bf((n < 64) ? Wv[k*128 + 64 + n] : Weg[k*32 + 16 + (n-64)]);
    }
    for (int idx = t; idx < 8192; idx += 256){
        int o = idx >> 7, c = idx & 127;
        int r = (c & 7)*16 + (c >> 3);
        WoT[idx] = f2bf(Wo[r*64 + o]);
    }
    if (t < 80){
        bcoA[t] = (t < 64) ? bV[t]      : bEG[t-64];
        bcoB[t] = (t < 64) ? bV[64 + t] : bEG[16 + t-64];
    }
}

// ---------------------------------------------------------------------------
// k_projsm<PASS>: fused LayerNorm + [384,64]@[64,80] bf16 MFMA projection +
// in-block gated softmax. Block = (y, b), 256 threads; processes the FULL
// 384-row x-range in 3 chunks of 128 (each chunk = validated R4 k_proj body).
// S/G columns are kept in LDS sg[384][17] (pad-17 -> <=2-way banks) instead
// of round-tripping through HBM; after the 3 chunks, softmax over the block's
// row axis (which IS the reduction axis) + sigmoid gate -> bf16 A plane.
// PASS 0: y=i, rows are j (in-direction, +mask). PASS 1: y=j, rows are i.
// ---------------------------------------------------------------------------
template<int PASS>
__global__ __launch_bounds__(256) void k_projsm(
    const float* __restrict__ e, const float* __restrict__ lns, const float* __restrict__ lnb,
    const unsigned short* __restrict__ Wt, const float* __restrict__ bco,
    const float* __restrict__ mask,
    unsigned short* __restrict__ Vdst, unsigned short* __restrict__ Adst)
{
    __shared__ unsigned short Alds[128*72];
    __shared__ unsigned short Wlds[80*72];
    __shared__ float bcs[80];
    __shared__ float sg[384][17];
    const int tid = threadIdx.x;
    const int y  = blockIdx.x;
    const int b  = blockIdx.y;
    const int z8 = b * 8;

    // stage weight slice into padded LDS [80][72]
    for (int c = tid; c < 640; c += 256){
        int n = c >> 3, k8 = (c & 7) * 8;
        short8 v = *(const short8*)&Wt[c*8];
        *(short8*)&Wlds[n*72 + k8] = v;
    }
    if (tid < 80) bcs[tid] = bco[tid];

    const int lq = tid & 3;
    float scv[16], bsv[16];
    #pragma unroll
    for (int j = 0; j < 4; ++j){
        float4 s4 = *(const float4*)&lns[lq*16 + j*4];
        float4 b4 = *(const float4*)&lnb[lq*16 + j*4];
        scv[j*4+0]=s4.x; scv[j*4+1]=s4.y; scv[j*4+2]=s4.z; scv[j*4+3]=s4.w;
        bsv[j*4+0]=b4.x; bsv[j*4+1]=b4.y; bsv[j*4+2]=b4.z; bsv[j*4+3]=b4.w;
    }

    const int w = tid >> 6, l = tid & 63;
    const int lr = l & 15, lk = (l >> 4) * 8;
    const int rowoff = (l >> 4) * 4;

    for (int cx = 0; cx < 3; ++cx){
        const int x0 = cx * 128;
        __syncthreads();   // Wlds staged (cx=0) / prev chunk's Alds reads done

        // LayerNorm: 2 passes x 64 rows; 4 lanes per row, 16 elems/lane
        #pragma unroll
        for (int p = 0; p < 2; ++p){
            int lrow = p*64 + (tid >> 2);
            size_t gbase;
            if (PASS == 0) gbase = (((size_t)(b*NI + y)) * NI + x0 + lrow) * NE + lq*16;
            else           gbase = (((size_t)(b*NI + x0 + lrow)) * NI + y) * NE + lq*16;
            float xs[16];
            #pragma unroll
            for (int j = 0; j < 4; ++j){
                float4 x4 = *(const float4*)&e[gbase + j*4];
                xs[j*4+0]=x4.x; xs[j*4+1]=x4.y; xs[j*4+2]=x4.z; xs[j*4+3]=x4.w;
            }
            float s = 0.f, sq = 0.f;
            #pragma unroll
            for (int j = 0; j < 16; ++j){ s += xs[j]; sq += xs[j]*xs[j]; }
            s  += __shfl_xor(s, 1, 64);  s  += __shfl_xor(s, 2, 64);
            sq += __shfl_xor(sq, 1, 64); sq += __shfl_xor(sq, 2, 64);
            float mu = s * (1.f/64.f);
            float var = sq * (1.f/64.f) - mu*mu;
            float rs = rsqrtf(var + 1e-5f);
            short8 o0, o1;
            #pragma unroll
            for (int j = 0; j < 8; ++j){
                o0[j] = (short)f2bf((xs[j]   - mu)*rs*scv[j]   + bsv[j]);
                o1[j] = (short)f2bf((xs[j+8] - mu)*rs*scv[j+8] + bsv[j+8]);
            }
            *(short8*)&Alds[lrow*72 + lq*16]     = o0;
            *(short8*)&Alds[lrow*72 + lq*16 + 8] = o1;
        }
        __syncthreads();

        // MFMA: wave w owns rows w*32..w*32+31 (2 frags) x 80 cols (5 frags)
        floatx4 acc[2][5];
        #pragma unroll
        for (int mf = 0; mf < 2; ++mf)
            #pragma unroll
            for (int nf = 0; nf < 5; ++nf)
                acc[mf][nf] = (floatx4){0.f,0.f,0.f,0.f};

        #pragma unroll
        for (int ks = 0; ks < 2; ++ks){
            int kk = ks*32 + lk;
            short8 a0 = *(const short8*)&Alds[(w*32 +  0 + lr)*72 + kk];
            short8 a1 = *(const short8*)&Alds[(w*32 + 16 + lr)*72 + kk];
            #pragma unroll
            for (int nf = 0; nf < 5; ++nf){
                short8 bfr = *(const short8*)&Wlds[(nf*16 + lr)*72 + kk];
                acc[0][nf] = __builtin_amdgcn_mfma_f32_16x16x32_bf16(a0, bfr, acc[0][nf], 0, 0, 0);
                acc[1][nf] = __builtin_amdgcn_mfma_f32_16x16x32_bf16(a1, bfr, acc[1][nf], 0, 0, 0);
            }
        }

        // Epilogue: V columns -> coalesced global; S/G columns -> LDS sg
        #pragma unroll
        for (int mf = 0; mf < 2; ++mf){
            const int bl = x0 + w*32 + mf*16 + rowoff;
            #pragma unroll
            for (int nf = 0; nf < 4; ++nf){
                int ca = nf*16 + lr;
                int dd = ca >> 3, h = ca & 7;
                float bia = bcs[ca];
                US4 v;
                v.x = f2bf(acc[mf][nf][0] + bia);
                v.y = f2bf(acc[mf][nf][1] + bia);
                v.z = f2bf(acc[mf][nf][2] + bia);
                v.w = f2bf(acc[mf][nf][3] + bia);
                *(US4*)&Vdst[(size_t)(z8 + h)*VPLANE_E + (size_t)(y*8 + dd)*KPAD + bl] = v;
            }
            {
                float bia = bcs[64 + lr];
                #pragma unroll
                for (int q = 0; q < 4; ++q)
                    sg[bl + q][lr] = acc[mf][4][q] + bia;
            }
        }
    }
    __syncthreads();

    // Softmax + gate over the block's 384-row axis; wave w owns h = 2w, 2w+1
    float mv[6];
    if (PASS == 0){
        #pragma unroll
        for (int q = 0; q < 6; ++q)
            mv[q] = mask[((size_t)b*NI + y)*NI + l + q*64];
    }
    #pragma unroll
    for (int hh = 0; hh < 2; ++hh){
        const int h = w*2 + hh;
        float sv[6], gv[6];
        float m = -1e30f;
        #pragma unroll
        for (int q = 0; q < 6; ++q){
            int j = l + q*64;
            float mk = (PASS == 0) ? mv[q] : 0.f;
            sv[q] = sg[j][h]     + mk;
            gv[q] = sg[j][8 + h] + mk;
            m = fmaxf(m, sv[q]);
        }
        m = wave_max(m);
        float ssum = 0.f;
        #pragma unroll
        for (int q = 0; q < 6; ++q){ sv[q] = expf(sv[q] - m); ssum += sv[q]; }
        ssum = wave_sum(ssum);
        float inv = 1.f / ssum;
        unsigned short* dst = Adst + (size_t)(z8 + h)*APLANE_E + (size_t)y*KPAD;
        #pragma unroll
        for (int q = 0; q < 6; ++q){
            float sig = 1.f / (1.f + expf(-gv[q]));
            dst[l + q*64] = f2bf(sv[q] * inv * sig);
        }
    }
}

// ---------------------------------------------------------------------------
// k_gemm: C[384,3072] = A[384,384] @ B^T (B stored [n][k]), bf16 MFMA.
// (exact revert to validated round-7 kernel: 51.9 us, 0 bank conflicts)
// Block tile 128x256, 256 threads = 2x2 waves, wave tile 64x128 (acc 4x8).
// Staging via global_load_lds width=16 into LINEAR LDS tiles; XOR chunk-
// swizzle on the GLOBAL source address, same XOR on ds_read_b128.
// 1D grid 1152, bijective XCD swizzle (144 blocks = 4 whole planes per XCD).
// ---------------------------------------------------------------------------
__global__ __launch_bounds__(256, 2) void k_gemm(
    const unsigned short* __restrict__ AinP, const unsigned short* __restrict__ AoutP,
    const unsigned short* __restrict__ VinP, const unsigned short* __restrict__ VoutP,
    unsigned short* __restrict__ VaIn, unsigned short* __restrict__ VaOut)
{
    __shared__ unsigned short Al[128*64];    // 16 KB, linear [row][64], swizzled chunks
    __shared__ unsigned short Bl[256*64];    // 32 KB
    const int tid = threadIdx.x;

    // XCD-aware bijective swizzle: 1152 blocks = 8 XCDs x 144
    const int L = blockIdx.x;
    const int W = (L & 7) * 144 + (L >> 3);
    const int nt = W % 12;
    const int mt = (W / 12) % 3;
    const int z  = W / 36;
    const int dir = z >> 4, bh = z & 15;
    const unsigned short* Ap = (dir ? AoutP : AinP) + (size_t)bh * APLANE_E;
    const unsigned short* Bp = (dir ? VoutP : VinP) + (size_t)bh * VPLANE_E;
    unsigned short* Cp = (dir ? VaOut : VaIn) + (size_t)bh * PLANE;
    const int m0 = mt*128, n0 = nt*256;

    const int w = tid >> 6, l = tid & 63;
    const int lr = l & 15, lk4 = l >> 4;
    const int wr = w >> 1, wc = w & 1;

    // staging lane geometry: lane l covers (row_in_inst = l>>3, physical chunk = l&7)
    const int srow8  = l >> 3;                      // 0..7
    const int schunk = (l & 7) ^ (srow8 & 7);       // logical chunk to fetch

    floatx4 acc[4][8];
    #pragma unroll
    for (int mf = 0; mf < 4; ++mf)
        #pragma unroll
        for (int nf = 0; nf < 8; ++nf)
            acc[mf][nf] = (floatx4){0.f,0.f,0.f,0.f};

    for (int kb = 0; kb < 6; ++kb){
        const int k0 = kb*64;
        __syncthreads();                            // prev compute done before overwrite
        // A-tile: 16 insts of 8 rows; wave w owns insts [4w, 4w+4)
        #pragma unroll
        for (int t = 0; t < 4; ++t){
            int inst = w*4 + t;
            gl_lds16(&Ap[(size_t)(m0 + inst*8 + srow8)*KPAD + k0 + schunk*8],
                     &Al[inst*512]);
        }
        // B-tile: 32 insts; wave w owns insts [8w, 8w+8)
        #pragma unroll
        for (int t = 0; t < 8; ++t){
            int inst = w*8 + t;
            gl_lds16(&Bp[(size_t)(n0 + inst*8 + srow8)*KPAD + k0 + schunk*8],
                     &Bl[inst*512]);
        }
        asm volatile("s_waitcnt vmcnt(0)" ::: "memory");
        __syncthreads();
        #pragma unroll
        for (int ks = 0; ks < 2; ++ks){
            const int cx = ((ks*4 + lk4) ^ (lr & 7)) * 8;   // swizzled chunk offset (shorts)
            short8 a[4], b[8];
            #pragma unroll
            for (int mf = 0; mf < 4; ++mf)
                a[mf] = *(const short8*)&Al[(wr*64 + mf*16 + lr)*64 + cx];
            #pragma unroll
            for (int nf = 0; nf < 8; ++nf)
                b[nf] = *(const short8*)&Bl[(wc*128 + nf*16 + lr)*64 + cx];
            #pragma unroll
            for (int mf = 0; mf < 4; ++mf)
                #pragma unroll
                for (int nf = 0; nf < 8; ++nf)
                    acc[mf][nf] = __builtin_amdgcn_mfma_f32_16x16x32_bf16(a[mf], b[nf], acc[mf][nf], 0, 0, 0);
        }
    }

    const int rowoff = lk4 * 4;
    #pragma unroll
    for (int mf = 0; mf < 4; ++mf)
        #pragma unroll
        for (int q = 0; q < 4; ++q){
            int i = m0 + wr*64 + mf*16 + rowoff + q;
            #pragma unroll
            for (int nf = 0; nf < 8; ++nf){
                int n = n0 + wc*128 + nf*16 + lr;
                Cp[(size_t)i*MCOLS + n] = f2bf(acc[mf][nf][q]);
            }
        }
}

// ---------------------------------------------------------------------------
// k_f2: epilogue GEMM via MFMA, no A-staging.
// (unchanged from validated round-5 kernel)
// ---------------------------------------------------------------------------
__global__ __launch_bounds__(192) void k_f2(
    const unsigned short* __restrict__ Vain, const unsigned short* __restrict__ Vaout,
    const unsigned short* __restrict__ WoT, const float* __restrict__ bO,
    float* __restrict__ out)
{
    __shared__ unsigned short wl[64*136];
    const int tid = threadIdx.x;
    const int jt = blockIdx.x, i = blockIdx.y, b = blockIdx.z;

    for (int cc = tid; cc < 1024; cc += 192){     // stage WoT [64][128] -> [64][136]
        int o = cc >> 4, k8 = (cc & 15) * 8;
        short8 v = *(const short8*)&WoT[cc*8];
        *(short8*)&wl[o*136 + k8] = v;
    }

    const int w = tid >> 6, l = tid & 63;
    const int lr = l & 15, lk = (l >> 4) * 8;
    const int j0 = jt*192 + w*64;

    float bias[4];
    #pragma unroll
    for (int nf = 0; nf < 4; ++nf) bias[nf] = bO[nf*16 + lr];

    __syncthreads();

    short8 bfr[4][4];
    #pragma unroll
    for (int ks = 0; ks < 4; ++ks)
        #pragma unroll
        for (int nf = 0; nf < 4; ++nf)
            bfr[ks][nf] = *(const short8*)&wl[(nf*16 + lr)*136 + ks*32 + lk];

    floatx4 acc[4][4];
    #pragma unroll
    for (int mf = 0; mf < 4; ++mf)
        #pragma unroll
        for (int nf = 0; nf < 4; ++nf)
            acc[mf][nf] = (floatx4){0.f,0.f,0.f,0.f};

    const int p_lane = (l >> 4);
    #pragma unroll
    for (int mf = 0; mf < 4; ++mf){
        int j = j0 + mf*16 + lr;
        short8 a[4];
        #pragma unroll
        for (int ks = 0; ks < 4; ++ks){
            int p = ks*4 + p_lane;
            const unsigned short* src = (p >= 8) ? Vaout : Vain;
            int h = p & 7;
            a[ks] = *(const short8*)&src[(size_t)(b*8 + h)*PLANE + (size_t)i*MCOLS + (size_t)j*8];
        }
        #pragma unroll
        for (int ks = 0; ks < 4; ++ks)
            #pragma unroll
            for (int nf = 0; nf < 4; ++nf)
                acc[mf][nf] = __builtin_amdgcn_mfma_f32_16x16x32_bf16(a[ks], bfr[ks][nf], acc[mf][nf], 0, 0, 0);
    }

    const int rowoff = (l >> 4) * 4;
    const size_t obase = ((size_t)(b*NI + i)) * NI;
    #pragma unroll
    for (int mf = 0; mf < 4; ++mf)
        #pragma unroll
        for (int q = 0; q < 4; ++q){
            int j = j0 + mf*16 + rowoff + q;
            #pragma unroll
            for (int nf = 0; nf < 4; ++nf)
                out[(obase + j)*NE + nf*16 + lr] = acc[mf][nf][q] + bias[nf];
        }
}

// ---------------------------------------------------------------------------
extern "C" void kernel_launch(void* const* d_in, const int* in_sizes, int n_in,
                              void* d_out, int out_size, void* d_ws, size_t ws_size,
                              hipStream_t stream)
{
    const float* e    = (const float*)d_in[0];
    const float* mask = (const float*)d_in[1];
    const float* lns  = (const float*)d_in[2];
    const float* lnb  = (const float*)d_in[3];
    const float* Wv   = (const float*)d_in[4];
    const float* bV   = (const float*)d_in[5];
    const float* Weg  = (const float*)d_in[6];
    const float* bEG  = (const float*)d_in[7];
    const float* Wo   = (const float*)d_in[8];
    const float* bO   = (const float*)d_in[9];

    // ws layout (bytes): VinP 38,535,168 | VoutP ends 77,070,336 |
    // AinP/AoutP 4,816,896 each (ends 86,704,128) | WtA/WtB/WoT/bco ~37 KB
    // (ends 86,741,632, 16B-aligned) | VaIn 37,748,736 | VaOut (ends
    // 162,239,104) < 188,743,680. S/G planes eliminated (fused into k_projsm).
    unsigned short* VinP  = (unsigned short*)d_ws;
    unsigned short* VoutP = VinP  + (size_t)16 * VPLANE_E;
    unsigned short* AinP  = VoutP + (size_t)16 * VPLANE_E;
    unsigned short* AoutP = AinP  + (size_t)16 * APLANE_E;
    unsigned short* WtA   = AoutP + (size_t)16 * APLANE_E;
    unsigned short* WtB   = WtA + 5120;
    unsigned short* WoT   = WtB + 5120;
    float* bcoA = (float*)(WoT + 8192);
    float* bcoB = bcoA + 80;
    unsigned short* VaIn  = (unsigned short*)(bcoB + 80);
    unsigned short* VaOut = VaIn + (size_t)16 * PLANE;

    k_w<<<1, 256, 0, stream>>>(Wv, Weg, bV, bEG, Wo, WtA, WtB, bcoA, bcoB, WoT);
    k_projsm<0><<<dim3(NI, NB), 256, 0, stream>>>(e, lns, lnb, WtA, bcoA, mask, VinP,  AinP);
    k_projsm<1><<<dim3(NI, NB), 256, 0, stream>>>(e, lns, lnb, WtB, bcoB, mask, VoutP, AoutP);
    k_gemm<<<dim3(1152), 256, 0, stream>>>(AinP, AoutP, VinP, VoutP, VaIn, VaOut);
    k_f2  <<<dim3(2, NI, NB), 192, 0, stream>>>(VaIn, VaOut, WoT, bO, (float*)d_out);
}

// Round 11
// 154.826 us; speedup vs baseline: 1.1965x; 1.0821x over previous
//
#include <hip/hip_runtime.h>
#include <hip/hip_bf16.h>

// Problem constants
#define NB 2
#define NI 384
#define NE 64
#define NH 8
#define NNI (NI*NI)                 // 147456
#define NROWS (NB*NNI)              // 294912
#define MCOLS (NI*8)                // 3072
#define PLANE ((size_t)NI*MCOLS)    // 1179648 elems per (b,h) Va plane
#define KPAD 392                    // padded K stride for bf16 planes (784 B rows, 16B-aligned)
#define VPLANE_E ((size_t)MCOLS*KPAD)   // 1204224 elems per V plane
#define APLANE_E ((size_t)NI*KPAD)      // 150528 elems per A plane

typedef __attribute__((ext_vector_type(8))) short short8;
typedef __attribute__((ext_vector_type(4))) float floatx4;

struct alignas(8) US4 { unsigned short x, y, z, w; };

__device__ __forceinline__ float bf2f(unsigned short u){ return __uint_as_float(((unsigned)u) << 16); }
__device__ __forceinline__ unsigned short f2bf(float f){
    unsigned x = __float_as_uint(f);
    x += 0x7fffu + ((x >> 16) & 1u);          // round-to-nearest-even
    return (unsigned short)(x >> 16);
}

__device__ __forceinline__ float wave_sum(float v){
    #pragma unroll
    for (int m = 32; m > 0; m >>= 1) v += __shfl_xor(v, m, 64);
    return v;
}
__device__ __forceinline__ float wave_max(float v){
    #pragma unroll
    for (int m = 32; m > 0; m >>= 1) v = fmaxf(v, __shfl_xor(v, m, 64));
    return v;
}

// async global->LDS, 16B per lane; LDS dest is wave-uniform base + lane*16
__device__ __forceinline__ void gl_lds16(const unsigned short* g, unsigned short* l){
    __builtin_amdgcn_global_load_lds(
        (__attribute__((address_space(1))) void*)(g),
        (__attribute__((address_space(3))) void*)(l), 16, 0, 0);
}

// ---------------------------------------------------------------------------
// k_w: weight prep (unchanged from validated round-5 kernel).
// ---------------------------------------------------------------------------
__global__ __launch_bounds__(256) void k_w(
    const float* __restrict__ Wv, const float* __restrict__ Weg,
    const float* __restrict__ bV, const float* __restrict__ bEG,
    const float* __restrict__ Wo,
    unsigned short* __restrict__ WtA, unsigned short* __restrict__ WtB,
    float* __restrict__ bcoA, float* __restrict__ bcoB,
    unsigned short* __restrict__ WoT)
{
    const int t = threadIdx.x;
    for (int idx = t; idx < 5120; idx += 256){
        int n = idx >> 6, k = idx & 63;
        WtA[idx] = f2bf((n < 64) ? Wv[k*128 + n]      : Weg[k*32 + (n-64)]);
        WtB[idx] = f2bf((n < 64) ? Wv[k*128 + 64 + n] : Weg[k*32 + 16 + (n-64)]);
    }
    for (int idx = t; idx < 8192; idx += 256){
        int o = idx >> 7, c = idx & 127;
        int r = (c & 7)*16 + (c >> 3);
        WoT[idx] = f2bf(Wo[r*64 + o]);
    }
    if (t < 80){
        bcoA[t] = (t < 64) ? bV[t]      : bEG[t-64];
        bcoB[t] = (t < 64) ? bV[64 + t] : bEG[16 + t-64];
    }
}

// ---------------------------------------------------------------------------
// k_projsm (merged): fused LayerNorm + [384,64]@[64,80] bf16 MFMA projection
// + in-block gated softmax. Grid (y, b, pass), 256 threads; 3 chunks of 128
// rows. Changes vs validated R10 version:
//  - Alds/Wlds shrunk to [*][64] with the k_gemm-validated XOR chunk swizzle
//    (write chunk c at c^(row&7); read chunk (ks*4+lk4)^(lr&7)) -> LDS
//    53.1 KB -> 3 blocks/CU (was 2).
//  - e loads for chunk cx+1 issued right after the Alds-ready barrier, so
//    their latency hides under MFMA+epilogue (register double-buffer).
//  - Both passes in one launch (pass = blockIdx.z; uniform branch).
// ---------------------------------------------------------------------------
__global__ __launch_bounds__(256, 3) void k_projsm(
    const float* __restrict__ e, const float* __restrict__ lns, const float* __restrict__ lnb,
    const unsigned short* __restrict__ WtA, const unsigned short* __restrict__ WtB,
    const float* __restrict__ bcoA, const float* __restrict__ bcoB,
    const float* __restrict__ mask,
    unsigned short* __restrict__ VinP, unsigned short* __restrict__ VoutP,
    unsigned short* __restrict__ AinP, unsigned short* __restrict__ AoutP)
{
    __shared__ unsigned short Alds[128*64];   // 16 KB, XOR-swizzled chunks
    __shared__ unsigned short Wlds[80*64];    // 10 KB, XOR-swizzled chunks
    __shared__ float bcs[80];
    __shared__ float sg[384][17];             // 26.1 KB
    const int tid = threadIdx.x;
    const int y    = blockIdx.x;
    const int b    = blockIdx.y;
    const int pass = blockIdx.z;
    const int z8 = b * 8;

    const unsigned short* Wt = pass ? WtB : WtA;
    const float* bco         = pass ? bcoB : bcoA;
    unsigned short* Vdst     = pass ? VoutP : VinP;
    unsigned short* Adst     = pass ? AoutP : AinP;

    // stage weight slice into swizzled LDS [80][64]
    for (int c = tid; c < 640; c += 256){
        int n = c >> 3, pos = (c & 7) ^ (n & 7);
        short8 v = *(const short8*)&Wt[c*8];
        *(short8*)&Wlds[n*64 + pos*8] = v;
    }
    if (tid < 80) bcs[tid] = bco[tid];

    const int lq = tid & 3;
    float scv[16], bsv[16];
    #pragma unroll
    for (int j = 0; j < 4; ++j){
        float4 s4 = *(const float4*)&lns[lq*16 + j*4];
        float4 b4 = *(const float4*)&lnb[lq*16 + j*4];
        scv[j*4+0]=s4.x; scv[j*4+1]=s4.y; scv[j*4+2]=s4.z; scv[j*4+3]=s4.w;
        bsv[j*4+0]=b4.x; bsv[j*4+1]=b4.y; bsv[j*4+2]=b4.z; bsv[j*4+3]=b4.w;
    }

    const int w = tid >> 6, l = tid & 63;
    const int lr = l & 15, lk4 = l >> 4;
    const int rowoff = lk4 * 4;

    auto LOAD = [&](float (&xs)[2][16], int cx){
        #pragma unroll
        for (int p = 0; p < 2; ++p){
            int lrow = p*64 + (tid >> 2);
            size_t gbase;
            if (pass == 0) gbase = (((size_t)(b*NI + y)) * NI + cx*128 + lrow) * NE + lq*16;
            else           gbase = (((size_t)(b*NI + cx*128 + lrow)) * NI + y) * NE + lq*16;
            #pragma unroll
            for (int j = 0; j < 4; ++j){
                float4 x4 = *(const float4*)&e[gbase + j*4];
                xs[p][j*4+0]=x4.x; xs[p][j*4+1]=x4.y; xs[p][j*4+2]=x4.z; xs[p][j*4+3]=x4.w;
            }
        }
    };

    auto LNWRITE = [&](const float (&xs)[2][16]){
        #pragma unroll
        for (int p = 0; p < 2; ++p){
            int lrow = p*64 + (tid >> 2);
            float s = 0.f, sq = 0.f;
            #pragma unroll
            for (int j = 0; j < 16; ++j){ s += xs[p][j]; sq += xs[p][j]*xs[p][j]; }
            s  += __shfl_xor(s, 1, 64);  s  += __shfl_xor(s, 2, 64);
            sq += __shfl_xor(sq, 1, 64); sq += __shfl_xor(sq, 2, 64);
            float mu = s * (1.f/64.f);
            float var = sq * (1.f/64.f) - mu*mu;
            float rs = rsqrtf(var + 1e-5f);
            short8 o0, o1;
            #pragma unroll
            for (int j = 0; j < 8; ++j){
                o0[j] = (short)f2bf((xs[p][j]   - mu)*rs*scv[j]   + bsv[j]);
                o1[j] = (short)f2bf((xs[p][j+8] - mu)*rs*scv[j+8] + bsv[j+8]);
            }
            const int sw = lrow & 7;
            *(short8*)&Alds[lrow*64 + ((lq*2    ) ^ sw)*8] = o0;
            *(short8*)&Alds[lrow*64 + ((lq*2 + 1) ^ sw)*8] = o1;
        }
    };

    float xsA[2][16], xsB[2][16];
    LOAD(xsA, 0);

    #pragma unroll
    for (int cx = 0; cx < 3; ++cx){
        const int x0 = cx * 128;
        __syncthreads();   // Wlds staged (cx=0) / prev chunk's Alds reads done
        if (cx & 1) LNWRITE(xsB); else LNWRITE(xsA);
        __syncthreads();   // Alds ready
        if (cx == 0) LOAD(xsB, 1);           // prefetch: hides under MFMA+epilogue
        else if (cx == 1) LOAD(xsA, 2);

        // MFMA: wave w owns rows w*32..w*32+31 (2 frags) x 80 cols (5 frags)
        floatx4 acc[2][5];
        #pragma unroll
        for (int mf = 0; mf < 2; ++mf)
            #pragma unroll
            for (int nf = 0; nf < 5; ++nf)
                acc[mf][nf] = (floatx4){0.f,0.f,0.f,0.f};

        #pragma unroll
        for (int ks = 0; ks < 2; ++ks){
            const int ch = ((ks*4 + lk4) ^ (lr & 7)) * 8;
            short8 a0 = *(const short8*)&Alds[(w*32 +  0 + lr)*64 + ch];
            short8 a1 = *(const short8*)&Alds[(w*32 + 16 + lr)*64 + ch];
            #pragma unroll
            for (int nf = 0; nf < 5; ++nf){
                short8 bfr = *(const short8*)&Wlds[(nf*16 + lr)*64 + ch];
                acc[0][nf] = __builtin_amdgcn_mfma_f32_16x16x32_bf16(a0, bfr, acc[0][nf], 0, 0, 0);
                acc[1][nf] = __builtin_amdgcn_mfma_f32_16x16x32_bf16(a1, bfr, acc[1][nf], 0, 0, 0);
            }
        }

        // Epilogue: V columns -> coalesced global; S/G columns -> LDS sg
        #pragma unroll
        for (int mf = 0; mf < 2; ++mf){
            const int bl = x0 + w*32 + mf*16 + rowoff;
            #pragma unroll
            for (int nf = 0; nf < 4; ++nf){
                int ca = nf*16 + lr;
                int dd = ca >> 3, h = ca & 7;
                float bia = bcs[ca];
                US4 v;
                v.x = f2bf(acc[mf][nf][0] + bia);
                v.y = f2bf(acc[mf][nf][1] + bia);
                v.z = f2bf(acc[mf][nf][2] + bia);
                v.w = f2bf(acc[mf][nf][3] + bia);
                *(US4*)&Vdst[(size_t)(z8 + h)*VPLANE_E + (size_t)(y*8 + dd)*KPAD + bl] = v;
            }
            {
                float bia = bcs[64 + lr];
                #pragma unroll
                for (int q = 0; q < 4; ++q)
                    sg[bl + q][lr] = acc[mf][4][q] + bia;
            }
        }
    }
    __syncthreads();

    // Softmax + gate over the block's 384-row axis; wave w owns h = 2w, 2w+1
    float mv[6];
    if (pass == 0){
        #pragma unroll
        for (int q = 0; q < 6; ++q)
            mv[q] = mask[((size_t)b*NI + y)*NI + l + q*64];
    }
    #pragma unroll
    for (int hh = 0; hh < 2; ++hh){
        const int h = w*2 + hh;
        float sv[6], gv[6];
        float m = -1e30f;
        #pragma unroll
        for (int q = 0; q < 6; ++q){
            int j = l + q*64;
            float mk = (pass == 0) ? mv[q] : 0.f;
            sv[q] = sg[j][h]     + mk;
            gv[q] = sg[j][8 + h] + mk;
            m = fmaxf(m, sv[q]);
        }
        m = wave_max(m);
        float ssum = 0.f;
        #pragma unroll
        for (int q = 0; q < 6; ++q){ sv[q] = expf(sv[q] - m); ssum += sv[q]; }
        ssum = wave_sum(ssum);
        float inv = 1.f / ssum;
        unsigned short* dst = Adst + (size_t)(z8 + h)*APLANE_E + (size_t)y*KPAD;
        #pragma unroll
        for (int q = 0; q < 6; ++q){
            float sig = 1.f / (1.f + expf(-gv[q]));
            dst[l + q*64] = f2bf(sv[q] * inv * sig);
        }
    }
}

// ---------------------------------------------------------------------------
// k_gemm: C[384,3072] = A[384,384] @ B^T (B stored [n][k]), bf16 MFMA.
// (unchanged validated round-7 kernel: 51.9 us, 0 bank conflicts)
// ---------------------------------------------------------------------------
__global__ __launch_bounds__(256, 2) void k_gemm(
    const unsigned short* __restrict__ AinP, const unsigned short* __restrict__ AoutP,
    const unsigned short* __restrict__ VinP, const unsigned short* __restrict__ VoutP,
    unsigned short* __restrict__ VaIn, unsigned short* __restrict__ VaOut)
{
    __shared__ unsigned short Al[128*64];    // 16 KB, linear [row][64], swizzled chunks
    __shared__ unsigned short Bl[256*64];    // 32 KB
    const int tid = threadIdx.x;

    // XCD-aware bijective swizzle: 1152 blocks = 8 XCDs x 144
    const int L = blockIdx.x;
    const int W = (L & 7) * 144 + (L >> 3);
    const int nt = W % 12;
    const int mt = (W / 12) % 3;
    const int z  = W / 36;
    const int dir = z >> 4, bh = z & 15;
    const unsigned short* Ap = (dir ? AoutP : AinP) + (size_t)bh * APLANE_E;
    const unsigned short* Bp = (dir ? VoutP : VinP) + (size_t)bh * VPLANE_E;
    unsigned short* Cp = (dir ? VaOut : VaIn) + (size_t)bh * PLANE;
    const int m0 = mt*128, n0 = nt*256;

    const int w = tid >> 6, l = tid & 63;
    const int lr = l & 15, lk4 = l >> 4;
    const int wr = w >> 1, wc = w & 1;

    // staging lane geometry: lane l covers (row_in_inst = l>>3, physical chunk = l&7)
    const int srow8  = l >> 3;                      // 0..7
    const int schunk = (l & 7) ^ (srow8 & 7);       // logical chunk to fetch

    floatx4 acc[4][8];
    #pragma unroll
    for (int mf = 0; mf < 4; ++mf)
        #pragma unroll
        for (int nf = 0; nf < 8; ++nf)
            acc[mf][nf] = (floatx4){0.f,0.f,0.f,0.f};

    for (int kb = 0; kb < 6; ++kb){
        const int k0 = kb*64;
        __syncthreads();                            // prev compute done before overwrite
        #pragma unroll
        for (int t = 0; t < 4; ++t){
            int inst = w*4 + t;
            gl_lds16(&Ap[(size_t)(m0 + inst*8 + srow8)*KPAD + k0 + schunk*8],
                     &Al[inst*512]);
        }
        #pragma unroll
        for (int t = 0; t < 8; ++t){
            int inst = w*8 + t;
            gl_lds16(&Bp[(size_t)(n0 + inst*8 + srow8)*KPAD + k0 + schunk*8],
                     &Bl[inst*512]);
        }
        asm volatile("s_waitcnt vmcnt(0)" ::: "memory");
        __syncthreads();
        #pragma unroll
        for (int ks = 0; ks < 2; ++ks){
            const int cx = ((ks*4 + lk4) ^ (lr & 7)) * 8;   // swizzled chunk offset (shorts)
            short8 a[4], b[8];
            #pragma unroll
            for (int mf = 0; mf < 4; ++mf)
                a[mf] = *(const short8*)&Al[(wr*64 + mf*16 + lr)*64 + cx];
            #pragma unroll
            for (int nf = 0; nf < 8; ++nf)
                b[nf] = *(const short8*)&Bl[(wc*128 + nf*16 + lr)*64 + cx];
            #pragma unroll
            for (int mf = 0; mf < 4; ++mf)
                #pragma unroll
                for (int nf = 0; nf < 8; ++nf)
                    acc[mf][nf] = __builtin_amdgcn_mfma_f32_16x16x32_bf16(a[mf], b[nf], acc[mf][nf], 0, 0, 0);
        }
    }

    const int rowoff = lk4 * 4;
    #pragma unroll
    for (int mf = 0; mf < 4; ++mf)
        #pragma unroll
        for (int q = 0; q < 4; ++q){
            int i = m0 + wr*64 + mf*16 + rowoff + q;
            #pragma unroll
            for (int nf = 0; nf < 8; ++nf){
                int n = n0 + wc*128 + nf*16 + lr;
                Cp[(size_t)i*MCOLS + n] = f2bf(acc[mf][nf][q]);
            }
        }
}

// ---------------------------------------------------------------------------
// k_f2: epilogue GEMM via MFMA, no A-staging.
// (unchanged from validated round-5 kernel)
// ---------------------------------------------------------------------------
__global__ __launch_bounds__(192) void k_f2(
    const unsigned short* __restrict__ Vain, const unsigned short* __restrict__ Vaout,
    const unsigned short* __restrict__ WoT, const float* __restrict__ bO,
    float* __restrict__ out)
{
    __shared__ unsigned short wl[64*136];
    const int tid = threadIdx.x;
    const int jt = blockIdx.x, i = blockIdx.y, b = blockIdx.z;

    for (int cc = tid; cc < 1024; cc += 192){     // stage WoT [64][128] -> [64][136]
        int o = cc >> 4, k8 = (cc & 15) * 8;
        short8 v = *(const short8*)&WoT[cc*8];
        *(short8*)&wl[o*136 + k8] = v;
    }

    const int w = tid >> 6, l = tid & 63;
    const int lr = l & 15, lk = (l >> 4) * 8;
    const int j0 = jt*192 + w*64;

    float bias[4];
    #pragma unroll
    for (int nf = 0; nf < 4; ++nf) bias[nf] = bO[nf*16 + lr];

    __syncthreads();

    short8 bfr[4][4];
    #pragma unroll
    for (int ks = 0; ks < 4; ++ks)
        #pragma unroll
        for (int nf = 0; nf < 4; ++nf)
            bfr[ks][nf] = *(const short8*)&wl[(nf*16 + lr)*136 + ks*32 + lk];

    floatx4 acc[4][4];
    #pragma unroll
    for (int mf = 0; mf < 4; ++mf)
        #pragma unroll
        for (int nf = 0; nf < 4; ++nf)
            acc[mf][nf] = (floatx4){0.f,0.f,0.f,0.f};

    const int p_lane = (l >> 4);
    #pragma unroll
    for (int mf = 0; mf < 4; ++mf){
        int j = j0 + mf*16 + lr;
        short8 a[4];
        #pragma unroll
        for (int ks = 0; ks < 4; ++ks){
            int p = ks*4 + p_lane;
            const unsigned short* src = (p >= 8) ? Vaout : Vain;
            int h = p & 7;
            a[ks] = *(const short8*)&src[(size_t)(b*8 + h)*PLANE + (size_t)i*MCOLS + (size_t)j*8];
        }
        #pragma unroll
        for (int ks = 0; ks < 4; ++ks)
            #pragma unroll
            for (int nf = 0; nf < 4; ++nf)
                acc[mf][nf] = __builtin_amdgcn_mfma_f32_16x16x32_bf16(a[ks], bfr[ks][nf], acc[mf][nf], 0, 0, 0);
    }

    const int rowoff = (l >> 4) * 4;
    const size_t obase = ((size_t)(b*NI + i)) * NI;
    #pragma unroll
    for (int mf = 0; mf < 4; ++mf)
        #pragma unroll
        for (int q = 0; q < 4; ++q){
            int j = j0 + mf*16 + rowoff + q;
            #pragma unroll
            for (int nf = 0; nf < 4; ++nf)
                out[(obase + j)*NE + nf*16 + lr] = acc[mf][nf][q] + bias[nf];
        }
}

// ---------------------------------------------------------------------------
extern "C" void kernel_launch(void* const* d_in, const int* in_sizes, int n_in,
                              void* d_out, int out_size, void* d_ws, size_t ws_size,
                              hipStream_t stream)
{
    const float* e    = (const float*)d_in[0];
    const float* mask = (const float*)d_in[1];
    const float* lns  = (const float*)d_in[2];
    const float* lnb  = (const float*)d_in[3];
    const float* Wv   = (const float*)d_in[4];
    const float* bV   = (const float*)d_in[5];
    const float* Weg  = (const float*)d_in[6];
    const float* bEG  = (const float*)d_in[7];
    const float* Wo   = (const float*)d_in[8];
    const float* bO   = (const float*)d_in[9];

    unsigned short* VinP  = (unsigned short*)d_ws;
    unsigned short* VoutP = VinP  + (size_t)16 * VPLANE_E;
    unsigned short* AinP  = VoutP + (size_t)16 * VPLANE_E;
    unsigned short* AoutP = AinP  + (size_t)16 * APLANE_E;
    unsigned short* WtA   = AoutP + (size_t)16 * APLANE_E;
    unsigned short* WtB   = WtA + 5120;
    unsigned short* WoT   = WtB + 5120;
    float* bcoA = (float*)(WoT + 8192);
    float* bcoB = bcoA + 80;
    unsigned short* VaIn  = (unsigned short*)(bcoB + 80);
    unsigned short* VaOut = VaIn + (size_t)16 * PLANE;

    k_w<<<1, 256, 0, stream>>>(Wv, Weg, bV, bEG, Wo, WtA, WtB, bcoA, bcoB, WoT);
    k_projsm<<<dim3(NI, NB, 2), 256, 0, stream>>>(e, lns, lnb, WtA, WtB, bcoA, bcoB,
                                                  mask, VinP, VoutP, AinP, AoutP);
    k_gemm<<<dim3(1152), 256, 0, stream>>>(AinP, AoutP, VinP, VoutP, VaIn, VaOut);
    k_f2  <<<dim3(2, NI, NB), 192, 0, stream>>>(VaIn, VaOut, WoT, bO, (float*)d_out);
}